// Round 6
// baseline (117.784 us; speedup 1.0000x reference)
//
#include <hip/hip_runtime.h>

#define BATCH   256
#define NCOL    576
#define MROW    144
#define ZLIFT   24
#define NIT     3
#define ROW_DEG 15
#define NEDGE   (MROW * ROW_DEG)                 // 2160
#define NSCIT   ((MROW/ZLIFT) * (NCOL/ZLIFT) * NIT)  // 432
#define TPB     512                              // 8 waves; 1 block/CU
#define ROWS_PER_WAVE (MROW / 8)                 // 18

// Single fused kernel: one block (512 threads, 8 waves) per frame.
//  - Each block extracts its own row column-lists from dense H via
//    ballot+popcount (ascending order preserved — argmin tie-break needs it).
//    H is 331 KB -> L2-resident after the first few blocks.
//  - Thread tid<144 owns check row tid; its column indices, channel LLRs,
//    previous E messages, and CSC slots live in REGISTERS across iterations.
//  - E_s is stored in CSC (column-major) order so the variable-node phase
//    reads contiguous runs — no indirection, no per-iteration atomics.
//  - Final iteration's column sum is fused into the output write.
__global__ __launch_bounds__(TPB) void ldpc_fused_kernel(
    const float* __restrict__ r,
    const float* __restrict__ alpha,
    const float* __restrict__ beta,
    const int*   __restrict__ H,
    float*       __restrict__ out)
{
    __shared__ float r_s[NCOL];
    __shared__ float cs[2][NCOL];      // ping-pong column sums
    __shared__ float E_s[NEDGE];       // CSC-ordered extrinsic messages
    __shared__ float a_s[NSCIT];
    __shared__ float b_s[NSCIT];
    __shared__ int   cdeg[NCOL];       // per-column degree
    __shared__ int   cstart[NCOL];     // exclusive prefix of cdeg
    __shared__ int   c_s[NEDGE];       // packed n | sidx<<16 (row-major)

    const int b    = blockIdx.x;
    const int tid  = threadIdx.x;
    const int wave = tid >> 6;
    const int lane = tid & 63;

    // ---- stage inputs ----
    for (int n = tid; n < NCOL; n += TPB) {
        r_s[n]   = r[(size_t)b * NCOL + n];
        cs[0][n] = 0.0f;
        cdeg[n]  = 0;
    }
    if (tid < NSCIT) { a_s[tid] = alpha[tid]; b_s[tid] = beta[tid]; }

    // ---- per-block H extraction: wave w handles rows [w*18, w*18+18) ----
    #pragma unroll
    for (int j = 0; j < ROWS_PER_WAVE; ++j) {
        const int row  = wave * ROWS_PER_WAVE + j;
        const int srow = (row / ZLIFT) * (NCOL / ZLIFT);
        const int* hrow = H + (size_t)row * NCOL;
        int base = 0;
        #pragma unroll
        for (int c0 = 0; c0 < NCOL; c0 += 64) {
            const int n = c0 + lane;
            const int present = (hrow[n] != 0) ? 1 : 0;
            const unsigned long long mask = __ballot(present);
            if (present) {
                const int rank = __popcll(mask & ((1ull << lane) - 1ull));
                const int idx = base + rank;
                if (idx < ROW_DEG)
                    c_s[row * ROW_DEG + idx] = n | ((srow + n / ZLIFT) << 16);
            }
            base += __popcll(mask);
        }
    }
    __syncthreads();

    // ---- row-owned register state + CSC rank via atomics ----
    const bool is_row = (tid < MROW);
    int   pk_r[ROW_DEG];    // packed n | sidx<<16
    float r_r[ROW_DEG];     // channel LLR at each edge's column
    float E_r[ROW_DEG];     // previous-iteration extrinsic message
    int   slot_r[ROW_DEG];  // CSC slot (rank first, then + cstart[n])
    if (is_row) {
        #pragma unroll
        for (int k = 0; k < ROW_DEG; ++k) {
            const int p = c_s[tid * ROW_DEG + k];
            pk_r[k] = p;
            const int n = p & 0xFFFF;
            r_r[k]  = r_s[n];
            E_r[k]  = 0.0f;
            slot_r[k] = atomicAdd(&cdeg[n], 1);
        }
    }
    __syncthreads();

    // Wave 0: exclusive prefix scan cdeg -> cstart (9 cols/lane, shuffle scan).
    if (tid < 64) {
        int local[9];
        int run = 0;
        #pragma unroll
        for (int j = 0; j < 9; ++j) { local[j] = cdeg[tid * 9 + j]; run += local[j]; }
        int scan = run;
        #pragma unroll
        for (int off = 1; off < 64; off <<= 1) {
            int up = __shfl_up(scan, off);
            if (tid >= off) scan += up;
        }
        int acc = scan - run;   // exclusive
        #pragma unroll
        for (int j = 0; j < 9; ++j) { cstart[tid * 9 + j] = acc; acc += local[j]; }
    }
    __syncthreads();

    if (is_row) {
        #pragma unroll
        for (int k = 0; k < ROW_DEG; ++k)
            slot_r[k] += cstart[pk_r[k] & 0xFFFF];
    }
    // (no barrier needed: slot_r is register-private, E_s not yet read)

    // ---- iterations ----
    for (int it = 0; it < NIT; ++it) {
        float* prev = cs[it & 1];
        float* next = cs[(it + 1) & 1];

        // Check-node phase: M = r + prevsum - E_prev recomputed on the fly;
        // min-2 with strict < (== top_k first-occurrence tie-break); sign prod.
        if (is_row) {
            float vals[ROW_DEG];
            float min1 = INFINITY, min2 = INFINITY;
            int   kmin = -1;
            float sprod = 1.0f;
            #pragma unroll
            for (int k = 0; k < ROW_DEG; ++k) {
                const int n = pk_r[k] & 0xFFFF;
                const float v = r_r[k] + prev[n] - E_r[k];
                vals[k] = v;
                const float av = fabsf(v);
                const float s = (v > 0.0f) ? 1.0f : ((v < 0.0f) ? -1.0f : 0.0f);
                sprod *= s;
                if (av < min1)      { min2 = min1; min1 = av; kmin = k; }
                else if (av < min2) { min2 = av; }
            }
            #pragma unroll
            for (int k = 0; k < ROW_DEG; ++k) {
                const int sidx = pk_r[k] >> 16;
                const float v = vals[k];
                const float s = (v > 0.0f) ? 1.0f : ((v < 0.0f) ? -1.0f : 0.0f);
                const float a  = a_s[sidx * NIT + it];
                const float bt = b_s[sidx * NIT + it];
                const float eabs = (k == kmin) ? min2 : min1;
                float mag = eabs - bt;
                if (mag < 0.0f) mag = 0.0f;
                const float E = a * (sprod * s) * mag;
                E_r[k] = E;
                E_s[slot_r[k]] = E;
            }
        }
        __syncthreads();   // E_s complete

        // Variable-node phase: contiguous CSC gather.
        // Last iteration fuses straight into the posterior output write.
        if (it < NIT - 1) {
            for (int n = tid; n < NCOL; n += TPB) {
                const int s0  = cstart[n];
                const int deg = cdeg[n];
                float sum = 0.0f;
                for (int i = 0; i < deg; ++i) sum += E_s[s0 + i];
                next[n] = sum;
            }
            __syncthreads();   // next complete before reuse as prev
        } else {
            for (int n = tid; n < NCOL; n += TPB) {
                const int s0  = cstart[n];
                const int deg = cdeg[n];
                float sum = 0.0f;
                for (int i = 0; i < deg; ++i) sum += E_s[s0 + i];
                out[(size_t)b * NCOL + n] = r_s[n] + sum;
            }
        }
    }
}

extern "C" void kernel_launch(void* const* d_in, const int* in_sizes, int n_in,
                              void* d_out, int out_size, void* d_ws, size_t ws_size,
                              hipStream_t stream) {
    const float* r     = (const float*)d_in[0];
    const float* alpha = (const float*)d_in[1];
    const float* beta  = (const float*)d_in[2];
    const int*   H     = (const int*)d_in[3];
    float* out = (float*)d_out;
    (void)d_ws; (void)ws_size;

    ldpc_fused_kernel<<<BATCH, TPB, 0, stream>>>(r, alpha, beta, H, out);
}

// Round 7
// 71.452 us; speedup vs baseline: 1.6484x; 1.6484x over previous
//
#include <hip/hip_runtime.h>

#define BATCH   256
#define NCOL    576
#define MROW    144
#define ZLIFT   24
#define NIT     3
#define ROW_DEG 15
#define NEDGE   (MROW * ROW_DEG)                 // 2160
#define NSCIT   ((MROW/ZLIFT) * (NCOL/ZLIFT) * NIT)  // 432
#define TPB     512                              // 8 waves; 1 block/CU

// Kernel 1: one wave per check row. int4 loads (3 rounds instead of 9) +
// 4-ballot rank computation; ascending column order preserved (the argmin
// tie-break depends on it). Packs n | sidx<<16, sidx=(m/24)*24+n/24.
__global__ __launch_bounds__(256) void build_cols_kernel(
    const int* __restrict__ H, int* __restrict__ pk)
{
    const int wave = (blockIdx.x * blockDim.x + threadIdx.x) >> 6;
    const int lane = threadIdx.x & 63;
    if (wave >= MROW) return;
    const int4* row4 = (const int4*)(H + (size_t)wave * NCOL);
    const int srow = (wave / ZLIFT) * (NCOL / ZLIFT);
    const unsigned long long below = (1ull << lane) - 1ull;
    int base = 0;
    #pragma unroll
    for (int r0 = 0; r0 < 3; ++r0) {
        const int vidx = r0 * 64 + lane;        // int4 index within row, 0..143
        int4 h = make_int4(0, 0, 0, 0);
        if (vidx < NCOL / 4) h = row4[vidx];
        const int b0 = h.x != 0, b1 = h.y != 0, b2 = h.z != 0, b3 = h.w != 0;
        const unsigned long long m0 = __ballot(b0);
        const unsigned long long m1 = __ballot(b1);
        const unsigned long long m2 = __ballot(b2);
        const unsigned long long m3 = __ballot(b3);
        const int cnt_below = __popcll(m0 & below) + __popcll(m1 & below)
                            + __popcll(m2 & below) + __popcll(m3 & below);
        const int bits[4] = {b0, b1, b2, b3};
        const int n0 = vidx * 4;
        int pref = 0;
        #pragma unroll
        for (int c = 0; c < 4; ++c) {
            if (bits[c]) {
                const int idx = base + cnt_below + pref;
                const int n = n0 + c;
                if (idx < ROW_DEG)
                    pk[wave * ROW_DEG + idx] = n | ((srow + n / ZLIFT) << 16);
                ++pref;
            }
        }
        base += __popcll(m0) + __popcll(m1) + __popcll(m2) + __popcll(m3);
    }
}

// Kernel 2: one block (512 threads, 8 waves) per frame.
// Thread tid<144 owns check row tid; column indices, channel LLRs, previous
// E messages, and CSC slots all live in REGISTERS. E_s is CSC-ordered so the
// variable-node gather reads contiguous runs (no indirection, no per-iter
// atomics). Iter-0 reads no colsum (M=r exactly); single colsum buffer
// (check-read and gather-write are barrier-separated); last gather fused
// into the posterior output write.
__global__ __launch_bounds__(TPB) void ldpc_decode_kernel(
    const float* __restrict__ r,
    const float* __restrict__ alpha,
    const float* __restrict__ beta,
    const int*   __restrict__ pk,
    float*       __restrict__ out)
{
    __shared__ float r_s[NCOL];
    __shared__ float colsum[NCOL];
    __shared__ float E_s[NEDGE];       // CSC-ordered extrinsic messages
    __shared__ float a_s[NSCIT];
    __shared__ float b_s[NSCIT];
    __shared__ int   cdeg[NCOL];       // per-column degree
    __shared__ int   cstart[NCOL];     // exclusive prefix of cdeg

    const int b   = blockIdx.x;
    const int tid = threadIdx.x;

    // ---- setup ----
    for (int n = tid; n < NCOL; n += TPB) {
        r_s[n]  = r[(size_t)b * NCOL + n];
        cdeg[n] = 0;
    }
    if (tid < NSCIT) { a_s[tid] = alpha[tid]; b_s[tid] = beta[tid]; }
    __syncthreads();

    const bool is_row = (tid < MROW);
    int   pk_r[ROW_DEG];    // packed n | sidx<<16
    float r_r[ROW_DEG];     // channel LLR at each edge's column
    float E_r[ROW_DEG];     // previous-iteration extrinsic message
    int   slot_r[ROW_DEG];  // CSC slot (rank first, then + cstart[n])
    if (is_row) {
        #pragma unroll
        for (int k = 0; k < ROW_DEG; ++k) {
            const int p = pk[tid * ROW_DEG + k];
            pk_r[k] = p;
            const int n = p & 0xFFFF;
            r_r[k]  = r_s[n];
            E_r[k]  = 0.0f;
            slot_r[k] = atomicAdd(&cdeg[n], 1);
        }
    }
    __syncthreads();

    // Wave 0: exclusive prefix scan cdeg -> cstart (9 cols/lane, shuffle scan).
    if (tid < 64) {
        int local[9];
        int run = 0;
        #pragma unroll
        for (int j = 0; j < 9; ++j) { local[j] = cdeg[tid * 9 + j]; run += local[j]; }
        int scan = run;
        #pragma unroll
        for (int off = 1; off < 64; off <<= 1) {
            int up = __shfl_up(scan, off);
            if (tid >= off) scan += up;
        }
        int acc = scan - run;   // exclusive
        #pragma unroll
        for (int j = 0; j < 9; ++j) { cstart[tid * 9 + j] = acc; acc += local[j]; }
    }
    __syncthreads();

    if (is_row) {
        #pragma unroll
        for (int k = 0; k < ROW_DEG; ++k)
            slot_r[k] += cstart[pk_r[k] & 0xFFFF];
    }
    // (no barrier needed: slot_r is register-private, E_s not yet read)

    // ---- iterations ----
    for (int it = 0; it < NIT; ++it) {
        // Check-node phase: M = r + colsum - E_prev recomputed on the fly
        // (it==0: M = r exactly — no colsum read); min-2 with strict <
        // (== top_k first-occurrence tie-break); extrinsic sign product.
        if (is_row) {
            float vals[ROW_DEG];
            float min1 = INFINITY, min2 = INFINITY;
            int   kmin = -1;
            float sprod = 1.0f;
            #pragma unroll
            for (int k = 0; k < ROW_DEG; ++k) {
                float v;
                if (it == 0) {
                    v = r_r[k];
                } else {
                    const int n = pk_r[k] & 0xFFFF;
                    v = r_r[k] + colsum[n] - E_r[k];
                }
                vals[k] = v;
                const float av = fabsf(v);
                const float s = (v > 0.0f) ? 1.0f : ((v < 0.0f) ? -1.0f : 0.0f);
                sprod *= s;
                if (av < min1)      { min2 = min1; min1 = av; kmin = k; }
                else if (av < min2) { min2 = av; }
            }
            #pragma unroll
            for (int k = 0; k < ROW_DEG; ++k) {
                const int sidx = pk_r[k] >> 16;
                const float v = vals[k];
                const float s = (v > 0.0f) ? 1.0f : ((v < 0.0f) ? -1.0f : 0.0f);
                const float a  = a_s[sidx * NIT + it];
                const float bt = b_s[sidx * NIT + it];
                const float eabs = (k == kmin) ? min2 : min1;
                float mag = eabs - bt;
                if (mag < 0.0f) mag = 0.0f;
                const float E = a * (sprod * s) * mag;
                E_r[k] = E;
                E_s[slot_r[k]] = E;
            }
        }
        __syncthreads();   // E_s complete (and all colsum reads done)

        // Variable-node phase: contiguous CSC gather (overwrite, no zeroing).
        // Last iteration fuses straight into the posterior output write.
        if (it < NIT - 1) {
            for (int n = tid; n < NCOL; n += TPB) {
                const int s0  = cstart[n];
                const int deg = cdeg[n];
                float sum = 0.0f;
                for (int i = 0; i < deg; ++i) sum += E_s[s0 + i];
                colsum[n] = sum;
            }
            __syncthreads();   // colsum complete before next check phase
        } else {
            for (int n = tid; n < NCOL; n += TPB) {
                const int s0  = cstart[n];
                const int deg = cdeg[n];
                float sum = 0.0f;
                for (int i = 0; i < deg; ++i) sum += E_s[s0 + i];
                out[(size_t)b * NCOL + n] = r_s[n] + sum;
            }
        }
    }
}

extern "C" void kernel_launch(void* const* d_in, const int* in_sizes, int n_in,
                              void* d_out, int out_size, void* d_ws, size_t ws_size,
                              hipStream_t stream) {
    const float* r     = (const float*)d_in[0];
    const float* alpha = (const float*)d_in[1];
    const float* beta  = (const float*)d_in[2];
    const int*   H     = (const int*)d_in[3];
    float* out = (float*)d_out;
    int*   pk  = (int*)d_ws;   // NEDGE packed ints

    build_cols_kernel<<<(MROW * 64 + 255) / 256, 256, 0, stream>>>(H, pk);
    ldpc_decode_kernel<<<BATCH, TPB, 0, stream>>>(r, alpha, beta, pk, out);
}

// Round 8
// 69.741 us; speedup vs baseline: 1.6889x; 1.0245x over previous
//
#include <hip/hip_runtime.h>

#define BATCH   256
#define NCOL    576
#define MROW    144
#define ZLIFT   24
#define NIT     3
#define ROW_DEG 15
#define PKSTR   16                               // pk row stride (int4-friendly)
#define NSCIT   ((MROW/ZLIFT) * (NCOL/ZLIFT) * NIT)  // 432
#define TPB     512                              // 8 waves; 1 block/CU
#define CCAP    18   // per-column capacity (max deg <= 17 proven: R3 cap-17 == R4 exact, bit-identical)
#define CSTR    19   // padded stride, odd -> LDS bank period 32 (conflict-free)

// Kernel 1: one wave per check row. int4 loads + 4-ballot rank computation;
// ascending column order preserved (argmin tie-break needs it).
// Packs n | sidx<<16 (sidx=(m/24)*24+n/24) at row stride PKSTR=16.
__global__ __launch_bounds__(256) void build_cols_kernel(
    const int* __restrict__ H, int* __restrict__ pk)
{
    const int wave = (blockIdx.x * blockDim.x + threadIdx.x) >> 6;
    const int lane = threadIdx.x & 63;
    if (wave >= MROW) return;
    const int4* row4 = (const int4*)(H + (size_t)wave * NCOL);
    const int srow = (wave / ZLIFT) * (NCOL / ZLIFT);
    const unsigned long long below = (1ull << lane) - 1ull;
    int base = 0;
    #pragma unroll
    for (int r0 = 0; r0 < 3; ++r0) {
        const int vidx = r0 * 64 + lane;        // int4 index within row, 0..143
        int4 h = make_int4(0, 0, 0, 0);
        if (vidx < NCOL / 4) h = row4[vidx];
        const int b0 = h.x != 0, b1 = h.y != 0, b2 = h.z != 0, b3 = h.w != 0;
        const unsigned long long m0 = __ballot(b0);
        const unsigned long long m1 = __ballot(b1);
        const unsigned long long m2 = __ballot(b2);
        const unsigned long long m3 = __ballot(b3);
        const int cnt_below = __popcll(m0 & below) + __popcll(m1 & below)
                            + __popcll(m2 & below) + __popcll(m3 & below);
        const int bits[4] = {b0, b1, b2, b3};
        const int n0 = vidx * 4;
        int pref = 0;
        #pragma unroll
        for (int c = 0; c < 4; ++c) {
            if (bits[c]) {
                const int idx = base + cnt_below + pref;
                const int n = n0 + c;
                if (idx < ROW_DEG)
                    pk[wave * PKSTR + idx] = n | ((srow + n / ZLIFT) << 16);
                ++pref;
            }
        }
        base += __popcll(m0) + __popcll(m1) + __popcll(m2) + __popcll(m3);
    }
}

// Kernel 2: one block (512 threads, 8 waves) per frame.
// Thread tid<144 owns check row tid; indices/LLRs/previous-E/slots in VGPRs.
// E messages live in a FIXED-STRIDE padded column layout (CSTR=19, CCAP=18):
// slot = n*19 + atomic-rank. The variable-node gather sums all 18 slots
// unconditionally (padding is exactly 0.0f, written once) -> fully unrolled,
// independent, bank-conflict-free LDS reads; no prefix scan, no cstart.
__global__ __launch_bounds__(TPB) void ldpc_decode_kernel(
    const float* __restrict__ r,
    const float* __restrict__ alpha,
    const float* __restrict__ beta,
    const int*   __restrict__ pk,
    float*       __restrict__ out)
{
    __shared__ float r_s[NCOL];
    __shared__ float colsum[NCOL];
    __shared__ float E_s[NCOL * CSTR];   // 10944 floats = 43.8 KB
    __shared__ float a_s[NSCIT];
    __shared__ float b_s[NSCIT];
    __shared__ int   cdeg[NCOL];         // atomic rank counters

    const int b   = blockIdx.x;
    const int tid = threadIdx.x;

    // ---- setup: stage inputs, zero E pad + rank counters ----
    for (int n = tid; n < NCOL; n += TPB) {
        r_s[n]  = r[(size_t)b * NCOL + n];
        cdeg[n] = 0;
    }
    for (int i = tid; i < NCOL * CSTR; i += TPB) E_s[i] = 0.0f;
    if (tid < NSCIT) { a_s[tid] = alpha[tid]; b_s[tid] = beta[tid]; }
    __syncthreads();   // B1: r_s/a_s/b_s staged, E_s zeroed, cdeg zeroed

    const bool is_row = (tid < MROW);
    int   pk_r[ROW_DEG];    // packed n | sidx<<16
    float r_r[ROW_DEG];     // channel LLR at each edge's column
    float E_r[ROW_DEG];     // previous-iteration extrinsic message
    int   slot_r[ROW_DEG];  // n*CSTR + rank (private; no barrier needed)
    if (is_row) {
        const int4* prow = (const int4*)(pk + tid * PKSTR);
        int4 q[4];
        #pragma unroll
        for (int j = 0; j < 4; ++j) q[j] = prow[j];
        const int* qi = (const int*)q;
        #pragma unroll
        for (int k = 0; k < ROW_DEG; ++k) {
            const int p = qi[k];
            pk_r[k] = p;
            const int n = p & 0xFFFF;
            r_r[k]  = r_s[n];
            E_r[k]  = 0.0f;
            slot_r[k] = n * CSTR + atomicAdd(&cdeg[n], 1);
        }
    }
    // (no barrier: slot_r is register-private; E_s writes occur below and all
    //  zero-init completed before B1)

    // ---- iterations ----
    for (int it = 0; it < NIT; ++it) {
        // Check-node phase: M = r + colsum - E_prev recomputed on the fly
        // (it==0: M = r exactly); min-2 with strict < (== top_k
        // first-occurrence tie-break); extrinsic sign product.
        if (is_row) {
            float vals[ROW_DEG];
            float min1 = INFINITY, min2 = INFINITY;
            int   kmin = -1;
            float sprod = 1.0f;
            #pragma unroll
            for (int k = 0; k < ROW_DEG; ++k) {
                float v;
                if (it == 0) {
                    v = r_r[k];
                } else {
                    const int n = pk_r[k] & 0xFFFF;
                    v = r_r[k] + colsum[n] - E_r[k];
                }
                vals[k] = v;
                const float av = fabsf(v);
                const float s = (v > 0.0f) ? 1.0f : ((v < 0.0f) ? -1.0f : 0.0f);
                sprod *= s;
                if (av < min1)      { min2 = min1; min1 = av; kmin = k; }
                else if (av < min2) { min2 = av; }
            }
            #pragma unroll
            for (int k = 0; k < ROW_DEG; ++k) {
                const int sidx = pk_r[k] >> 16;
                const float v = vals[k];
                const float s = (v > 0.0f) ? 1.0f : ((v < 0.0f) ? -1.0f : 0.0f);
                const float a  = a_s[sidx * NIT + it];
                const float bt = b_s[sidx * NIT + it];
                const float eabs = (k == kmin) ? min2 : min1;
                float mag = eabs - bt;
                if (mag < 0.0f) mag = 0.0f;
                const float E = a * (sprod * s) * mag;
                E_r[k] = E;
                E_s[slot_r[k]] = E;
            }
        }
        __syncthreads();   // E_s complete (and all colsum reads done)

        // Variable-node phase: fixed-width unrolled gather (pad slots are +0.0f,
        // so partial-sum order == exact CSC order -> bit-identical).
        if (it < NIT - 1) {
            for (int n = tid; n < NCOL; n += TPB) {
                const float* base = &E_s[n * CSTR];
                float sum = 0.0f;
                #pragma unroll
                for (int i = 0; i < CCAP; ++i) sum += base[i];
                colsum[n] = sum;
            }
            __syncthreads();   // colsum complete before next check phase
        } else {
            for (int n = tid; n < NCOL; n += TPB) {
                const float* base = &E_s[n * CSTR];
                float sum = 0.0f;
                #pragma unroll
                for (int i = 0; i < CCAP; ++i) sum += base[i];
                out[(size_t)b * NCOL + n] = r_s[n] + sum;
            }
        }
    }
}

extern "C" void kernel_launch(void* const* d_in, const int* in_sizes, int n_in,
                              void* d_out, int out_size, void* d_ws, size_t ws_size,
                              hipStream_t stream) {
    const float* r     = (const float*)d_in[0];
    const float* alpha = (const float*)d_in[1];
    const float* beta  = (const float*)d_in[2];
    const int*   H     = (const int*)d_in[3];
    float* out = (float*)d_out;
    int*   pk  = (int*)d_ws;   // MROW*PKSTR packed ints

    build_cols_kernel<<<(MROW * 64 + 255) / 256, 256, 0, stream>>>(H, pk);
    ldpc_decode_kernel<<<BATCH, TPB, 0, stream>>>(r, alpha, beta, pk, out);
}

// Round 9
// 65.579 us; speedup vs baseline: 1.7961x; 1.0635x over previous
//
#include <hip/hip_runtime.h>

#define BATCH   256
#define NCOL    576
#define MROW    144
#define ZLIFT   24
#define NIT     3
#define ROW_DEG 15
#define PKSTR   16                               // pk row stride (int4-friendly)
#define NSCIT   ((MROW/ZLIFT) * (NCOL/ZLIFT) * NIT)  // 432
#define TPB     576                              // 9 waves; == NCOL == 4*MROW
#define CCAP    18   // per-column capacity (max deg <= 17 proven: R3 cap-17 == R4 exact)
#define CSTR    19   // padded stride, odd -> LDS bank period 32 (conflict-free)

// Kernel 1: one wave per check row. int4 loads + 4-ballot rank computation;
// ascending column order preserved (argmin tie-break needs it).
// Packs n | sidx<<16 (sidx=(m/24)*24+n/24) at row stride PKSTR=16.
// Entry 15 of each row is a sentinel (0) so decode can safely int4-load it.
__global__ __launch_bounds__(256) void build_cols_kernel(
    const int* __restrict__ H, int* __restrict__ pk)
{
    const int wave = (blockIdx.x * blockDim.x + threadIdx.x) >> 6;
    const int lane = threadIdx.x & 63;
    if (wave >= MROW) return;
    const int4* row4 = (const int4*)(H + (size_t)wave * NCOL);
    const int srow = (wave / ZLIFT) * (NCOL / ZLIFT);
    const unsigned long long below = (1ull << lane) - 1ull;
    if (lane == 0) pk[wave * PKSTR + 15] = 0;   // sentinel pad entry
    int base = 0;
    #pragma unroll
    for (int r0 = 0; r0 < 3; ++r0) {
        const int vidx = r0 * 64 + lane;        // int4 index within row, 0..143
        int4 h = make_int4(0, 0, 0, 0);
        if (vidx < NCOL / 4) h = row4[vidx];
        const int b0 = h.x != 0, b1 = h.y != 0, b2 = h.z != 0, b3 = h.w != 0;
        const unsigned long long m0 = __ballot(b0);
        const unsigned long long m1 = __ballot(b1);
        const unsigned long long m2 = __ballot(b2);
        const unsigned long long m3 = __ballot(b3);
        const int cnt_below = __popcll(m0 & below) + __popcll(m1 & below)
                            + __popcll(m2 & below) + __popcll(m3 & below);
        const int bits[4] = {b0, b1, b2, b3};
        const int n0 = vidx * 4;
        int pref = 0;
        #pragma unroll
        for (int c = 0; c < 4; ++c) {
            if (bits[c]) {
                const int idx = base + cnt_below + pref;
                const int n = n0 + c;
                if (idx < ROW_DEG)
                    pk[wave * PKSTR + idx] = n | ((srow + n / ZLIFT) << 16);
                ++pref;
            }
        }
        base += __popcll(m0) + __popcll(m1) + __popcll(m2) + __popcll(m3);
    }
}

// Kernel 2: one block (576 threads, 9 waves) per frame; TPB == NCOL.
// Each check row is owned by 4 ADJACENT LANES (row = tid>>2, sub = tid&3);
// lane sub handles edges k in [4*sub, 4*sub+4) (sub 3: 3 real + 1 sentinel).
// Partial min-2/argmin/sign-product merged with 2 order-aware __shfl_xor
// steps (preserves top_k first-occurrence tie-break) — no extra barriers.
// E messages live in fixed-stride padded column layout (CSTR=19, CCAP=18):
// slot = n*19 + atomic rank; pads stay 0.0f so the gather is a fully
// unrolled 18-read sum, one column per thread.
__global__ __launch_bounds__(TPB) void ldpc_decode_kernel(
    const float* __restrict__ r,
    const float* __restrict__ alpha,
    const float* __restrict__ beta,
    const int*   __restrict__ pk,
    float*       __restrict__ out)
{
    __shared__ float  r_s[NCOL];
    __shared__ float  colsum[NCOL];
    __shared__ float  E_s[NCOL * CSTR];   // 10944 floats = 43.8 KB
    __shared__ float2 ab_s[NSCIT];        // interleaved {alpha, beta}
    __shared__ int    cdeg[NCOL];         // atomic rank counters

    const int b   = blockIdx.x;
    const int tid = threadIdx.x;
    const int row = tid >> 2;
    const int sub = tid & 3;

    // ---- setup: stage inputs, zero E + rank counters (tid == column id) ----
    r_s[tid]  = r[(size_t)b * NCOL + tid];
    cdeg[tid] = 0;
    #pragma unroll
    for (int j = 0; j < CSTR; ++j) E_s[j * NCOL + tid] = 0.0f;
    if (tid < NSCIT) ab_s[tid] = make_float2(alpha[tid], beta[tid]);
    __syncthreads();   // B1: staged + zeroed

    // ---- per-lane edge state (<=4 edges), one aligned int4 of pk ----
    const int4 q = *(const int4*)(pk + row * PKSTR + sub * 4);
    int pk_r[4] = {q.x, q.y, q.z, q.w};
    float r_r[4], E_r[4];
    int   slot_r[4];
    #pragma unroll
    for (int j = 0; j < 4; ++j) {
        const int kglob = sub * 4 + j;
        const int n = pk_r[j] & 0xFFFF;
        r_r[j] = r_s[n];               // sentinel reads r_s[0]: safe, unused
        E_r[j] = 0.0f;
        if (kglob < ROW_DEG)
            slot_r[j] = n * CSTR + atomicAdd(&cdeg[n], 1);
    }
    // (no barrier: slots register-private; E_s zero completed before B1)

    // ---- iterations ----
    for (int it = 0; it < NIT; ++it) {
        // Check phase: partial scan over own edges, then 2-step shuffle merge.
        float vals[4];
        float min1 = INFINITY, min2 = INFINITY;
        int   kmin = 1 << 30;
        float sprod = 1.0f;
        #pragma unroll
        for (int j = 0; j < 4; ++j) {
            const int kglob = sub * 4 + j;
            const bool val = (kglob < ROW_DEG);
            float v;
            if (it == 0) {
                v = r_r[j];
            } else {
                const int n = pk_r[j] & 0xFFFF;
                v = r_r[j] + colsum[n] - E_r[j];
            }
            vals[j] = v;
            const float av = val ? fabsf(v) : INFINITY;
            const float s = val ? ((v > 0.0f) ? 1.0f : ((v < 0.0f) ? -1.0f : 0.0f))
                                : 1.0f;
            sprod *= s;
            if (av < min1)      { min2 = min1; min1 = av; kmin = kglob; }
            else if (av < min2) { min2 = av; }
        }
        // Order-aware merge across the 4 sub-lanes (lower-k side wins ties ==
        // top_k first-occurrence).
        #pragma unroll
        for (int m = 1; m <= 2; m <<= 1) {
            const float o1 = __shfl_xor(min1, m);
            const float o2 = __shfl_xor(min2, m);
            const int   ok = __shfl_xor(kmin, m);
            const float os = __shfl_xor(sprod, m);
            const bool self_lo = ((sub & m) == 0);
            const float lo1 = self_lo ? min1 : o1;
            const float lo2 = self_lo ? min2 : o2;
            const int   lok = self_lo ? kmin : ok;
            const float hi1 = self_lo ? o1 : min1;
            const float hi2 = self_lo ? o2 : min2;
            const int   hik = self_lo ? ok : kmin;
            if (hi1 < lo1) { min1 = hi1; kmin = hik; min2 = fminf(hi2, lo1); }
            else           { min1 = lo1; kmin = lok; min2 = fminf(lo2, hi1); }
            sprod *= os;
        }
        // Extrinsic messages for own edges.
        #pragma unroll
        for (int j = 0; j < 4; ++j) {
            const int kglob = sub * 4 + j;
            if (kglob < ROW_DEG) {
                const int sidx = pk_r[j] >> 16;
                const float v = vals[j];
                const float s = (v > 0.0f) ? 1.0f : ((v < 0.0f) ? -1.0f : 0.0f);
                const float2 ab = ab_s[sidx * NIT + it];
                const float eabs = (kglob == kmin) ? min2 : min1;
                float mag = eabs - ab.y;
                if (mag < 0.0f) mag = 0.0f;
                const float E = ab.x * (sprod * s) * mag;
                E_r[j] = E;
                E_s[slot_r[j]] = E;
            }
        }
        __syncthreads();   // E_s complete; colsum reads done

        // Variable-node phase: one column per thread, fixed 18-read sum
        // (pads are exactly +0.0f). Last iteration fused into output write.
        const float* base = &E_s[tid * CSTR];
        float sum = 0.0f;
        #pragma unroll
        for (int i = 0; i < CCAP; ++i) sum += base[i];
        if (it < NIT - 1) {
            colsum[tid] = sum;
            __syncthreads();   // colsum complete before next check phase
        } else {
            out[(size_t)b * NCOL + tid] = r_s[tid] + sum;
        }
    }
}

extern "C" void kernel_launch(void* const* d_in, const int* in_sizes, int n_in,
                              void* d_out, int out_size, void* d_ws, size_t ws_size,
                              hipStream_t stream) {
    const float* r     = (const float*)d_in[0];
    const float* alpha = (const float*)d_in[1];
    const float* beta  = (const float*)d_in[2];
    const int*   H     = (const int*)d_in[3];
    float* out = (float*)d_out;
    int*   pk  = (int*)d_ws;   // MROW*PKSTR packed ints

    build_cols_kernel<<<(MROW * 64 + 255) / 256, 256, 0, stream>>>(H, pk);
    ldpc_decode_kernel<<<BATCH, TPB, 0, stream>>>(r, alpha, beta, pk, out);
}